// Round 9
// baseline (482.054 us; speedup 1.0000x reference)
//
#include <hip/hip_runtime.h>
#include <math.h>

// ---------------- constants from the reference ----------------
#define T_ 3
#define R_ 4
#define L_ 2
#define H_ 256
#define HEADS_ 8
#define D_ 32
#define FIN_ 128
#define OUT_ 128

typedef unsigned short bf16_t;
typedef __attribute__((ext_vector_type(8))) short bf16x8;
typedef __attribute__((ext_vector_type(4))) float f32x4;

__device__ __forceinline__ float bf2f(bf16_t h) {
    return __uint_as_float(((unsigned)h) << 16);
}
__device__ __forceinline__ float bflo(unsigned u) {   // low bf16 of packed u32
    return __uint_as_float(u << 16);
}
__device__ __forceinline__ float bfhi(unsigned u) {   // high bf16 of packed u32
    return __uint_as_float(u & 0xffff0000u);
}
__device__ __forceinline__ bf16_t f2bf(float f) {
    unsigned u = __float_as_uint(f);
    u += 0x7FFFu + ((u >> 16) & 1u);          // round-to-nearest-even
    return (bf16_t)(u >> 16);
}
__device__ __forceinline__ float gelu_exact(float x) {
    return 0.5f * x * (1.0f + erff(x * 0.70710678118654752440f));
}

// ---------------- zero fill ----------------
__global__ void zero_kernel(unsigned* __restrict__ p, long n) {
    long i = (long)blockIdx.x * blockDim.x + threadIdx.x;
    long stride = (long)gridDim.x * blockDim.x;
    for (; i < n; i += stride) p[i] = 0u;
}

// ---------------- dual transpose+convert ----------------
__global__ __launch_bounds__(256) void transconv2_kernel(
    const float* __restrict__ in0, bf16_t* __restrict__ out0,
    const float* __restrict__ in1, bf16_t* __restrict__ out1,
    int cnt0, int Rr, int Cc)
{
    __shared__ float Ls[64][65];
    const int tid = threadIdx.x;
    int z = blockIdx.z;
    const float* in;
    bf16_t* out;
    if (z < cnt0) { in = in0; out = out0; }
    else          { in = in1; out = out1; z -= cnt0; }
    const long base = (long)z * Rr * Cc;
    const int r0 = blockIdx.y * 64, c0 = blockIdx.x * 64;
    #pragma unroll
    for (int i = 0; i < 16; ++i) {
        int e = tid + i * 256; int row = e >> 6, col = e & 63;
        Ls[row][col] = in[base + (long)(r0 + row) * Cc + c0 + col];
    }
    __syncthreads();
    #pragma unroll
    for (int i = 0; i < 16; ++i) {
        int e = tid + i * 256; int row = e >> 6, col = e & 63;
        out[base + (long)(c0 + row) * Rr + r0 + col] = f2bf(Ls[col][row]);
    }
}

__global__ __launch_bounds__(256) void transconv_kernel(
    const float* __restrict__ in, bf16_t* __restrict__ out, int Rr, int Cc)
{
    __shared__ float Ls[64][65];
    const int tid = threadIdx.x;
    const long base = (long)blockIdx.z * Rr * Cc;
    const int r0 = blockIdx.y * 64, c0 = blockIdx.x * 64;
    #pragma unroll
    for (int i = 0; i < 16; ++i) {
        int e = tid + i * 256; int row = e >> 6, col = e & 63;
        Ls[row][col] = in[base + (long)(r0 + row) * Cc + c0 + col];
    }
    __syncthreads();
    #pragma unroll
    for (int i = 0; i < 16; ++i) {
        int e = tid + i * 256; int row = e >> 6, col = e & 63;
        out[base + (long)(c0 + row) * Rr + r0 + col] = f2bf(Ls[col][row]);
    }
}

// ---------------- fused relation weights (+bias, folded) ----------------
__global__ __launch_bounds__(256) void fuse_wT_kernel(
    const float* __restrict__ Wk, const float* __restrict__ Wv,
    const float* __restrict__ bk, const float* __restrict__ bv,
    const float* __restrict__ a_rel, const float* __restrict__ m_rel,
    bf16_t* __restrict__ WkvT, float* __restrict__ bkv)
{
    const int s = blockIdx.z;
    const int kv = s & 1, r = (s >> 1) & 3, l = s >> 3;
    const int SRCT[4] = {0, 1, 1, 1};
    const int st = SRCT[r];
    const float* W = (kv ? Wv : Wk) + ((long)l * T_ + st) * H_ * H_;
    const float* A = (kv ? m_rel : a_rel) + ((long)l * R_ + r) * HEADS_ * D_ * D_;
    const int hh = blockIdx.y, kt = blockIdx.x;
    __shared__ float As[32][33];
    __shared__ float Ws[64][33];
    const int tid = threadIdx.x;
    {
        int d = tid >> 3, e4 = (tid & 7) * 4;
        float4 v = *(const float4*)(A + (hh * D_ + d) * D_ + e4);
        As[d][e4] = v.x; As[d][e4 + 1] = v.y; As[d][e4 + 2] = v.z; As[d][e4 + 3] = v.w;
    }
    #pragma unroll
    for (int p = 0; p < 2; ++p) {
        int idx = p * 256 + tid;
        int row = idx >> 3, c4 = (idx & 7) * 4;
        float4 v = *(const float4*)(W + (long)(kt * 64 + row) * H_ + hh * 32 + c4);
        Ws[row][c4] = v.x; Ws[row][c4 + 1] = v.y; Ws[row][c4 + 2] = v.z; Ws[row][c4 + 3] = v.w;
    }
    __syncthreads();
    const int kl = tid & 63, eb = tid >> 6;
    #pragma unroll
    for (int ii = 0; ii < 8; ++ii) {
        int e = eb * 8 + ii;
        float acc = 0.f;
        #pragma unroll
        for (int d = 0; d < 32; ++d)
            acc += As[d][e] * Ws[kl][d];
        long rowIdx = (long)(s >> 1) * 512 + (kv * 256) + hh * 32 + e;
        WkvT[rowIdx * H_ + kt * 64 + kl] = f2bf(acc);
    }
    if (blockIdx.x == 0 && blockIdx.y == 0) {
        const float* b = (kv ? bv : bk) + ((long)l * T_ + st) * H_;
        const int bh = tid >> 5, be = tid & 31;
        float acc = 0.f;
        #pragma unroll
        for (int d = 0; d < D_; ++d)
            acc += b[bh * D_ + d] * A[(bh * D_ + d) * D_ + be];
        bkv[(long)(s >> 1) * 512 + kv * 256 + tid] = acc;
    }
}

// ---------------- CSR build (parallel scan) ----------------
__global__ void hist_kernel(const int* __restrict__ ei, int* __restrict__ indeg,
                            int Nn, int E)
{
    int idx = blockIdx.x * 256 + threadIdx.x;
    if (idx >= R_ * E) return;
    int r = idx / E, e = idx - r * E;
    int d = ei[(size_t)r * 2 * E + E + e];
    atomicAdd(indeg + (size_t)r * Nn + d, 1);
}

__global__ __launch_bounds__(256) void csr_part_kernel(
    const int* __restrict__ indeg, int* __restrict__ partials, int Nn, int nch)
{
    const int r = blockIdx.y, c = blockIdx.x, tid = threadIdx.x;
    const int lane = tid & 63, wave = tid >> 6;
    int idx = c * 256 + tid;
    int v = (idx < Nn) ? indeg[(size_t)r * Nn + idx] : 0;
    #pragma unroll
    for (int off = 1; off < 64; off <<= 1) v += __shfl_xor(v, off);
    __shared__ int wsum[4];
    if (lane == 0) wsum[wave] = v;
    __syncthreads();
    if (tid == 0) partials[r * nch + c] = wsum[0] + wsum[1] + wsum[2] + wsum[3];
}

__global__ __launch_bounds__(256) void csr_scanpart_kernel(
    int* __restrict__ partials, int nch)
{
    const int r = blockIdx.x, tid = threadIdx.x;
    __shared__ int sh[256];
    int v = (tid < nch) ? partials[r * nch + tid] : 0;
    sh[tid] = v;
    __syncthreads();
    for (int off = 1; off < 256; off <<= 1) {
        int u = (tid >= off) ? sh[tid - off] : 0;
        __syncthreads();
        sh[tid] += u;
        __syncthreads();
    }
    if (tid < nch) partials[r * nch + tid] = sh[tid] - v;   // exclusive
}

__global__ __launch_bounds__(256) void csr_write_kernel(
    const int* __restrict__ indeg, const int* __restrict__ partials,
    int* __restrict__ offs, int* __restrict__ cursor, int Nn, int nch)
{
    const int r = blockIdx.y, c = blockIdx.x, tid = threadIdx.x;
    int idx = c * 256 + tid;
    int v = (idx < Nn) ? indeg[(size_t)r * Nn + idx] : 0;
    __shared__ int sh[256];
    sh[tid] = v;
    __syncthreads();
    for (int off = 1; off < 256; off <<= 1) {
        int u = (tid >= off) ? sh[tid - off] : 0;
        __syncthreads();
        sh[tid] += u;
        __syncthreads();
    }
    int incl = sh[tid];
    int base = partials[r * nch + c];
    if (idx < Nn) {
        int excl = base + incl - v;
        offs[(size_t)r * (Nn + 1) + idx] = excl;
        cursor[(size_t)r * Nn + idx] = excl;
        if (idx == Nn - 1) offs[(size_t)r * (Nn + 1) + Nn] = base + incl;
    }
}

// esrc stores PRE-SCALED element offsets (src * 512) into a KV relation slice
__global__ void scatter_kernel(const int* __restrict__ ei, int* __restrict__ cursor,
                               int* __restrict__ esrc, int Nn, int E)
{
    int idx = blockIdx.x * 256 + threadIdx.x;
    if (idx >= R_ * E) return;
    int r = idx / E, e = idx - r * E;
    int s = ei[(size_t)r * 2 * E + e];
    int d = ei[(size_t)r * 2 * E + E + e];
    int pos = atomicAdd(cursor + (size_t)r * Nn + d, 1);
    esrc[(size_t)r * E + pos] = s * 512;
}

// ---------------- batched per-node attention aggregation (quad-chain) ----------------
// Per-relation INDEPENDENT softmax; normalized results summed (matches ref).
// 4 concurrent online-softmax chains per wave for MLP; deferred-max common path
// (rescale only when __any(lg - m > 8)); exact chain merges at the end.
#define MERGE(X, Y)                                                     \
    {                                                                   \
        float mm = fmaxf(m[X], m[Y]);                                   \
        float fx = (s[X] > 0.f) ? __expf(m[X] - mm) : 0.f;              \
        float fy = (s[Y] > 0.f) ? __expf(m[Y] - mm) : 0.f;              \
        s[X] = s[X] * fx + s[Y] * fy;                                   \
        a0[X] = a0[X] * fx + a0[Y] * fy;                                \
        a1[X] = a1[X] * fx + a1[Y] * fy;                                \
        a2[X] = a2[X] * fx + a2[Y] * fy;                                \
        a3[X] = a3[X] * fx + a3[Y] * fy;                                \
        m[X] = mm;                                                      \
    }

__global__ __launch_bounds__(256) void agg_all_kernel(
    const int* __restrict__ offs, const int* __restrict__ esrc,
    bf16_t* __restrict__ qbuf, const bf16_t* __restrict__ KV,
    const float* __restrict__ p_l, float scale, int Nn, int E)
{
    static const int NRELg[3] = {2, 1, 1};
    static const int R0g[3]  = {0, 1, 3};
    static const int R1g[3]  = {2, 0, 0};
    static const int DTg[3]  = {1, 0, 2};
    const int grp = blockIdx.y;
    const int wave = threadIdx.x >> 6, lane = threadIdx.x & 63;
    const int d = blockIdx.x * 4 + wave;
    if (d >= Nn) return;
    const int head = lane >> 3;
    const int dt = DTg[grp];
    const bool separate = (NRELg[grp] == 2);

    bf16_t* qrow = qbuf + ((size_t)dt * Nn + d) * H_;
    uint2 qu = ((const uint2*)qrow)[lane];
    float q0 = bflo(qu.x), q1 = bfhi(qu.x), q2 = bflo(qu.y), q3 = bfhi(qu.y);

    const int* es[4];
    const bf16_t* kv[4];
    float pr[4];
    int cur[4], end[4];

    {
        const int rA = R0g[grp];
        const int* esA = esrc + (size_t)rA * E;
        const bf16_t* kvA = KV + (size_t)rA * Nn * 512;
        float prA = p_l[rA * HEADS_ + head] * scale;
        int bA = offs[(size_t)rA * (Nn + 1) + d];
        int eA = offs[(size_t)rA * (Nn + 1) + d + 1];
        if (separate) {
            const int rB = R1g[grp];
            const int* esB = esrc + (size_t)rB * E;
            const bf16_t* kvB = KV + (size_t)rB * Nn * 512;
            float prB = p_l[rB * HEADS_ + head] * scale;
            int bB = offs[(size_t)rB * (Nn + 1) + d];
            int eB = offs[(size_t)rB * (Nn + 1) + d + 1];
            int mA = bA + ((eA - bA + 1) >> 1);
            int mB = bB + ((eB - bB + 1) >> 1);
            es[0] = esA; kv[0] = kvA; pr[0] = prA; cur[0] = bA; end[0] = mA;
            es[1] = esA; kv[1] = kvA; pr[1] = prA; cur[1] = mA; end[1] = eA;
            es[2] = esB; kv[2] = kvB; pr[2] = prB; cur[2] = bB; end[2] = mB;
            es[3] = esB; kv[3] = kvB; pr[3] = prB; cur[3] = mB; end[3] = eB;
        } else {
            int n = eA - bA;
            int c1 = bA + (n * 1) / 4, c2 = bA + (n * 2) / 4, c3 = bA + (n * 3) / 4;
            es[0] = esA; kv[0] = kvA; pr[0] = prA; cur[0] = bA; end[0] = c1;
            es[1] = esA; kv[1] = kvA; pr[1] = prA; cur[1] = c1; end[1] = c2;
            es[2] = esA; kv[2] = kvA; pr[2] = prA; cur[2] = c2; end[2] = c3;
            es[3] = esA; kv[3] = kvA; pr[3] = prA; cur[3] = c3; end[3] = eA;
        }
    }

    float m[4], s[4], a0[4], a1[4], a2[4], a3[4];
    #pragma unroll
    for (int c = 0; c < 4; ++c) {
        m[c] = -INFINITY; s[c] = 0.f;
        a0[c] = 0.f; a1[c] = 0.f; a2[c] = 0.f; a3[c] = 0.f;
    }

    for (;;) {
        bool h[4];
        bool anyh = false;
        #pragma unroll
        for (int c = 0; c < 4; ++c) { h[c] = cur[c] < end[c]; anyh |= h[c]; }
        if (!anyh) break;
        uint2 ku[4], vu[4];
        #pragma unroll
        for (int c = 0; c < 4; ++c) if (h[c]) {
            const bf16_t* row = kv[c] + es[c][cur[c]];
            ku[c] = ((const uint2*)row)[lane];
            vu[c] = ((const uint2*)(row + 256))[lane];
        }
        #pragma unroll
        for (int c = 0; c < 4; ++c) if (h[c]) {
            float dt_ = q0 * bflo(ku[c].x) + q1 * bfhi(ku[c].x)
                      + q2 * bflo(ku[c].y) + q3 * bfhi(ku[c].y);
            dt_ += __shfl_xor(dt_, 1);
            dt_ += __shfl_xor(dt_, 2);
            dt_ += __shfl_xor(dt_, 4);
            float lg = dt_ * pr[c];
            if (__any(lg - m[c] > 8.f)) {
                float mn = fmaxf(m[c], lg);
                float fac = __expf(m[c] - mn);
                float p = __expf(lg - mn);
                s[c] = s[c] * fac + p;
                a0[c] = a0[c] * fac + p * bflo(vu[c].x);
                a1[c] = a1[c] * fac + p * bfhi(vu[c].x);
                a2[c] = a2[c] * fac + p * bflo(vu[c].y);
                a3[c] = a3[c] * fac + p * bfhi(vu[c].y);
                m[c] = mn;
            } else {
                float p = __expf(lg - m[c]);
                s[c] += p;
                a0[c] += p * bflo(vu[c].x);
                a1[c] += p * bfhi(vu[c].x);
                a2[c] += p * bflo(vu[c].y);
                a3[c] += p * bfhi(vu[c].y);
            }
            ++cur[c];
        }
    }

    MERGE(0, 1)
    MERGE(2, 3)
    float t0, t1, t2, t3;
    if (separate) {
        float iA = (s[0] > 0.f) ? 1.f / s[0] : 0.f;
        float iB = (s[2] > 0.f) ? 1.f / s[2] : 0.f;
        t0 = a0[0] * iA + a0[2] * iB;
        t1 = a1[0] * iA + a1[2] * iB;
        t2 = a2[0] * iA + a2[2] * iB;
        t3 = a3[0] * iA + a3[2] * iB;
    } else {
        MERGE(0, 2)
        float iA = (s[0] > 0.f) ? 1.f / s[0] : 0.f;
        t0 = a0[0] * iA; t1 = a1[0] * iA; t2 = a2[0] * iA; t3 = a3[0] * iA;
    }
    ushort4 ou;
    ou.x = f2bf(gelu_exact(t0));
    ou.y = f2bf(gelu_exact(t1));
    ou.z = f2bf(gelu_exact(t2));
    ou.w = f2bf(gelu_exact(t3));
    ((ushort4*)qrow)[lane] = ou;
}

// ---------------- MFMA bf16 GEMM ----------------
#define ASTR 40
#define ESTR 72

template<typename TA, typename TC, int ACT_C>
__global__ __launch_bounds__(256) void mfma_gemm(
    const TA* __restrict__ A, const TA* __restrict__ A2, int zsplit,
    const bf16_t* __restrict__ BT,
    const float* __restrict__ bias, TC* __restrict__ C,
    int M, int K, int Nc,
    long strideA, long strideB, long strideBias, long strideC)
{
    const int gX = gridDim.x, gY = gridDim.y, gZ = gridDim.z;
    const int nwg = gX * gY * gZ;
    int flat = blockIdx.x + gX * (blockIdx.y + gY * blockIdx.z);
    const int qch = nwg >> 3, rch = nwg & 7;
    int xcd = flat & 7, cidx = flat >> 3;
    int swz = (xcd < rch ? xcd * (qch + 1) : rch * (qch + 1) + (xcd - rch) * qch) + cidx;
    const int by = swz / (gX * gZ);
    int rem = swz - by * (gX * gZ);
    const int bz = rem / gX;
    const int bx = rem - bz * gX;

    const TA* Ab = (bz < zsplit) ? (A + (long)bz * strideA) : A2;
    const bf16_t* Bb = BT + (long)bz * strideB;
    const float* biasb = bias + (long)bz * strideBias;
    TC* Cb = C + (long)bz * strideC;

    __shared__ bf16_t As[128 * ASTR];
    __shared__ bf16_t Bs[128 * ASTR];
    __shared__ bf16_t Es[4 * 16 * ESTR];
    const int tid = threadIdx.x;
    const int lane = tid & 63, wave = tid >> 6;
    const int wr = wave >> 1, wc = wave & 1;
    const int bm = by * 128, bn = bx * 128;
    const int r16 = lane & 15, g = lane >> 4;
    f32x4 acc[4][4] = {};

    for (int k0 = 0; k0 < K; k0 += 32) {
        #pragma unroll
        for (int p = 0; p < 2; ++p) {
            int idx = p * 256 + tid;
            int row = idx >> 2, seg = idx & 3;
            int grow = bm + row;
            bf16x8 av = {};
            if (grow < M) {
                if constexpr (sizeof(TA) == 2) {
                    av = *(const bf16x8*)(Ab + (long)grow * K + k0 + seg * 8);
                } else {
                    const float* sp = (const float*)Ab + (long)grow * K + k0 + seg * 8;
                    float4 f0 = *(const float4*)sp, f1 = *(const float4*)(sp + 4);
                    av[0] = (short)f2bf(f0.x); av[1] = (short)f2bf(f0.y);
                    av[2] = (short)f2bf(f0.z); av[3] = (short)f2bf(f0.w);
                    av[4] = (short)f2bf(f1.x); av[5] = (short)f2bf(f1.y);
                    av[6] = (short)f2bf(f1.z); av[7] = (short)f2bf(f1.w);
                }
            }
            *(bf16x8*)(As + row * ASTR + seg * 8) = av;
            bf16x8 bv = *(const bf16x8*)(Bb + (long)(bn + row) * K + k0 + seg * 8);
            *(bf16x8*)(Bs + row * ASTR + seg * 8) = bv;
        }
        __syncthreads();
        bf16x8 af[4], bfr[4];
        #pragma unroll
        for (int m = 0; m < 4; ++m)
            af[m] = *(const bf16x8*)(As + (wr * 64 + m * 16 + r16) * ASTR + g * 8);
        #pragma unroll
        for (int n = 0; n < 4; ++n)
            bfr[n] = *(const bf16x8*)(Bs + (wc * 64 + n * 16 + r16) * ASTR + g * 8);
        #pragma unroll
        for (int m = 0; m < 4; ++m)
            #pragma unroll
            for (int n = 0; n < 4; ++n)
                acc[m][n] = __builtin_amdgcn_mfma_f32_16x16x32_bf16(af[m], bfr[n], acc[m][n], 0, 0, 0);
        __syncthreads();
    }

    float bb[4];
    #pragma unroll
    for (int n = 0; n < 4; ++n)
        bb[n] = biasb[bn + wc * 64 + n * 16 + r16];

    if constexpr (sizeof(TC) == 2) {
        bf16_t* st = Es + wave * (16 * ESTR);
        #pragma unroll
        for (int m = 0; m < 4; ++m) {
            int rowbase = bm + wr * 64 + m * 16;
            #pragma unroll
            for (int n = 0; n < 4; ++n) {
                #pragma unroll
                for (int j = 0; j < 4; ++j) {
                    float vv = acc[m][n][j] + bb[n];
                    if (ACT_C) vv = fmaxf(vv, 0.f);
                    st[(g * 4 + j) * ESTR + n * 16 + r16] = f2bf(vv);
                }
            }
            #pragma unroll
            for (int p = 0; p < 2; ++p) {
                int row = p * 8 + (lane >> 3);
                int col0 = (lane & 7) * 8;
                int grow = rowbase + row;
                bf16x8 val = *(const bf16x8*)(st + row * ESTR + col0);
                if (grow < M)
                    *(bf16x8*)(Cb + (long)grow * Nc + bn + wc * 64 + col0) = val;
            }
        }
    } else {
        #pragma unroll
        for (int n = 0; n < 4; ++n) {
            int col = bn + wc * 64 + n * 16 + r16;
            #pragma unroll
            for (int m = 0; m < 4; ++m) {
                int rowbase = bm + wr * 64 + m * 16 + g * 4;
                #pragma unroll
                for (int j = 0; j < 4; ++j) {
                    int row = rowbase + j;
                    if (row < M) {
                        float vv = acc[m][n][j] + bb[n];
                        if (ACT_C) vv = fmaxf(vv, 0.f);
                        Cb[(long)row * Nc + col] = vv;
                    }
                }
            }
        }
    }
}

// ---------------- fused skip-gate + residual + LN + ReLU ----------------
__global__ __launch_bounds__(256) void skip_ln_kernel(
    bf16_t* __restrict__ h, const bf16_t* __restrict__ o,
    const float* __restrict__ skip, const float* __restrict__ ln_g,
    const float* __restrict__ ln_b, int Nn)
{
    const int wave = threadIdx.x >> 6;
    const int lane = threadIdx.x & 63;
    long row = (long)blockIdx.x * 4 + wave;
    long total = (long)T_ * Nn;
    if (row >= total) return;
    int t = (int)(row / Nn);
    float beta = 1.f / (1.f + expf(-skip[t]));
    float cb = 2.f - beta;
    ushort4 hv = reinterpret_cast<const ushort4*>(h + row * H_)[lane];
    ushort4 ov = reinterpret_cast<const ushort4*>(o + row * H_)[lane];
    float u0 = beta * bf2f(ov.x) + cb * bf2f(hv.x);
    float u1 = beta * bf2f(ov.y) + cb * bf2f(hv.y);
    float u2 = beta * bf2f(ov.z) + cb * bf2f(hv.z);
    float u3 = beta * bf2f(ov.w) + cb * bf2f(hv.w);
    float s1 = u0 + u1 + u2 + u3;
    float s2 = u0 * u0 + u1 * u1 + u2 * u2 + u3 * u3;
    #pragma unroll
    for (int off = 1; off < 64; off <<= 1) {
        s1 += __shfl_xor(s1, off);
        s2 += __shfl_xor(s2, off);
    }
    float mu = s1 * (1.f / H_);
    float var = s2 * (1.f / H_) - mu * mu;
    float inv = rsqrtf(var + 1e-5f);
    const float4 g = reinterpret_cast<const float4*>(ln_g + (size_t)t * H_)[lane];
    const float4 b = reinterpret_cast<const float4*>(ln_b + (size_t)t * H_)[lane];
    ushort4 r;
    r.x = f2bf(fmaxf((u0 - mu) * inv * g.x + b.x, 0.f));
    r.y = f2bf(fmaxf((u1 - mu) * inv * g.y + b.y, 0.f));
    r.z = f2bf(fmaxf((u2 - mu) * inv * g.z + b.z, 0.f));
    r.w = f2bf(fmaxf((u3 - mu) * inv * g.w + b.w, 0.f));
    reinterpret_cast<ushort4*>(h + row * H_)[lane] = r;
}

// ---------------- host side ----------------
extern "C" void kernel_launch(void* const* d_in, const int* in_sizes, int n_in,
                              void* d_out, int out_size, void* d_ws, size_t ws_size,
                              hipStream_t stream)
{
    const float* x     = (const float*)d_in[0];
    const int*   ei    = (const int*)  d_in[1];
    const float* Win   = (const float*)d_in[2];
    const float* b_in  = (const float*)d_in[3];
    const float* Wk    = (const float*)d_in[4];
    const float* bk    = (const float*)d_in[5];
    const float* Wq    = (const float*)d_in[6];
    const float* bq    = (const float*)d_in[7];
    const float* Wv    = (const float*)d_in[8];
    const float* bv    = (const float*)d_in[9];
    const float* Wa    = (const float*)d_in[10];
    const float* ba    = (const float*)d_in[11];
    const float* skip  = (const float*)d_in[12];
    const float* a_rel = (const float*)d_in[13];
    const float* m_rel = (const float*)d_in[14];
    const float* p_rel = (const float*)d_in[15];
    const float* ln_g  = (const float*)d_in[16];
    const float* ln_b  = (const float*)d_in[17];
    const float* Wout  = (const float*)d_in[18];
    const float* bout  = (const float*)d_in[19];
    float* out = (float*)d_out;

    const int N = in_sizes[0] / (T_ * FIN_);
    const int E = in_sizes[1] / (R_ * 2);
    const size_t NH = (size_t)N * H_;
    const int nch = (N + 255) / 256;
    const int ZBIG = 1 << 20;

    char* wp = (char*)d_ws;
    auto alloc = [&](size_t bytes) {
        void* r = wp;
        wp += (bytes + 255) & ~(size_t)255;
        return r;
    };
    bf16_t* h     = (bf16_t*)alloc(T_ * NH * 2);
    bf16_t* qbuf  = (bf16_t*)alloc(T_ * NH * 2);
    bf16_t* KV    = (bf16_t*)alloc((size_t)R_ * N * 512 * 2);
    int*    indeg = (int*)   alloc((size_t)R_ * N * 4);
    int*    offs  = (int*)   alloc((size_t)R_ * (N + 1) * 4);
    int*    cursor= (int*)   alloc((size_t)R_ * N * 4);
    int*    esrc  = (int*)   alloc((size_t)R_ * E * 4);
    int*    parts = (int*)   alloc((size_t)R_ * 256 * 4);
    bf16_t* WqT   = (bf16_t*)alloc((size_t)L_ * T_ * H_ * H_ * 2);
    bf16_t* WaT   = (bf16_t*)alloc((size_t)L_ * T_ * H_ * H_ * 2);
    bf16_t* WinT  = (bf16_t*)alloc((size_t)T_ * FIN_ * H_ * 2);
    bf16_t* WoutT = (bf16_t*)alloc((size_t)H_ * OUT_ * 2);
    bf16_t* WkvT  = (bf16_t*)alloc((size_t)L_ * R_ * 512 * H_ * 2);
    float*  bkv   = (float*) alloc((size_t)L_ * R_ * 512 * 4);

    bf16_t* obuf = KV;   // reuse of KV after agg consumes it

    if ((size_t)(wp - (char*)d_ws) > ws_size) return;   // clean-fail guard

    const float scale = 0.17677669529663688f;  // 1/sqrt(32)
    dim3 blk(256);
    auto gM = [](long M) { return (int)((M + 127) / 128); };

    // ---- weight preprocessing ----
    transconv2_kernel<<<dim3(4, 4, 2 * L_ * T_), blk, 0, stream>>>(
        Wq, WqT, Wa, WaT, L_ * T_, H_, H_);
    transconv_kernel<<<dim3(4, 2, T_), blk, 0, stream>>>(Win, WinT, FIN_, H_);
    transconv_kernel<<<dim3(2, 4, 1),  blk, 0, stream>>>(Wout, WoutT, H_, OUT_);
    fuse_wT_kernel<<<dim3(4, 8, 16), blk, 0, stream>>>(
        Wk, Wv, bk, bv, a_rel, m_rel, WkvT, bkv);

    // ---- CSR build (parallel) ----
    zero_kernel<<<256, blk, 0, stream>>>((unsigned*)indeg, (long)R_ * N);
    hist_kernel<<<(R_ * E + 255) / 256, blk, 0, stream>>>(ei, indeg, N, E);
    csr_part_kernel<<<dim3(nch, R_), blk, 0, stream>>>(indeg, parts, N, nch);
    csr_scanpart_kernel<<<R_, blk, 0, stream>>>(parts, nch);
    csr_write_kernel<<<dim3(nch, R_), blk, 0, stream>>>(indeg, parts, offs, cursor, N, nch);
    scatter_kernel<<<(R_ * E + 255) / 256, blk, 0, stream>>>(ei, cursor, esrc, N, E);

    // ---- input projection + relu ----
    mfma_gemm<float, bf16_t, 1><<<dim3(H_ / 128, gM(N), T_), blk, 0, stream>>>(
        x, x, ZBIG, WinT, b_in, h, N, FIN_, H_,
        (long)N * FIN_, (long)FIN_ * H_, H_, (long)NH);

    for (int l = 0; l < L_; ++l) {
        const long lw = (long)l * R_;
        // KV for all 4 relations in one z=4 launch
        mfma_gemm<bf16_t, bf16_t, 0><<<dim3(512 / 128, gM(N), 4), blk, 0, stream>>>(
            h, h + NH, 1, WkvT + lw * 512 * H_, bkv + lw * 512, KV,
            N, H_, 512, 0L, 512L * H_, 512L, (long)N * 512);
        // q for all 3 node types: z=3
        mfma_gemm<bf16_t, bf16_t, 0><<<dim3(H_ / 128, gM(N), 3), blk, 0, stream>>>(
            h, h, ZBIG, WqT + (size_t)l * T_ * H_ * H_, bq + (size_t)l * T_ * H_, qbuf,
            N, H_, H_, (long)NH, (long)H_ * H_, (long)H_, (long)NH);
        // batched per-node per-relation softmax aggregation + GELU (in place)
        agg_all_kernel<<<dim3((N + 3) / 4, 3), blk, 0, stream>>>(
            offs, esrc, qbuf, KV, p_rel + (size_t)l * R_ * HEADS_, scale, N, E);
        // o[t] = aggb[t] @ Wa[t] + ba[t] : z=3
        mfma_gemm<bf16_t, bf16_t, 0><<<dim3(H_ / 128, gM(N), 3), blk, 0, stream>>>(
            qbuf, qbuf, ZBIG, WaT + (size_t)l * T_ * H_ * H_, ba + (size_t)l * T_ * H_, obuf,
            N, H_, H_, (long)NH, (long)H_ * H_, (long)H_, (long)NH);
        // skip-gate + residual + LN + ReLU
        skip_ln_kernel<<<((size_t)T_ * N + 3) / 4, blk, 0, stream>>>(
            h, obuf, skip + l * T_, ln_g + (size_t)l * T_ * H_, ln_b + (size_t)l * T_ * H_, N);
    }

    // shared output projection: h bf16 -> out fp32
    mfma_gemm<bf16_t, float, 0><<<dim3(OUT_ / 128, gM((long)T_ * N), 1), blk, 0, stream>>>(
        h, h, ZBIG, WoutT, bout, out, T_ * N, H_, OUT_, 0L, 0L, 0L, 0L);
}

// Round 10
// 412.825 us; speedup vs baseline: 1.1677x; 1.1677x over previous
//
#include <hip/hip_runtime.h>
#include <math.h>

// ---------------- constants from the reference ----------------
#define T_ 3
#define R_ 4
#define L_ 2
#define H_ 256
#define HEADS_ 8
#define D_ 32
#define FIN_ 128
#define OUT_ 128

typedef unsigned short bf16_t;
typedef __attribute__((ext_vector_type(8))) short bf16x8;
typedef __attribute__((ext_vector_type(4))) float f32x4;

__device__ __forceinline__ float bf2f(bf16_t h) {
    return __uint_as_float(((unsigned)h) << 16);
}
__device__ __forceinline__ float bflo(unsigned u) {   // low bf16 of packed u32
    return __uint_as_float(u << 16);
}
__device__ __forceinline__ float bfhi(unsigned u) {   // high bf16 of packed u32
    return __uint_as_float(u & 0xffff0000u);
}
__device__ __forceinline__ bf16_t f2bf(float f) {
    unsigned u = __float_as_uint(f);
    u += 0x7FFFu + ((u >> 16) & 1u);          // round-to-nearest-even
    return (bf16_t)(u >> 16);
}
__device__ __forceinline__ float gelu_exact(float x) {
    return 0.5f * x * (1.0f + erff(x * 0.70710678118654752440f));
}

// ---------------- zero fill ----------------
__global__ void zero_kernel(unsigned* __restrict__ p, long n) {
    long i = (long)blockIdx.x * blockDim.x + threadIdx.x;
    long stride = (long)gridDim.x * blockDim.x;
    for (; i < n; i += stride) p[i] = 0u;
}

// ---------------- dual transpose+convert ----------------
__global__ __launch_bounds__(256) void transconv2_kernel(
    const float* __restrict__ in0, bf16_t* __restrict__ out0,
    const float* __restrict__ in1, bf16_t* __restrict__ out1,
    int cnt0, int Rr, int Cc)
{
    __shared__ float Ls[64][65];
    const int tid = threadIdx.x;
    int z = blockIdx.z;
    const float* in;
    bf16_t* out;
    if (z < cnt0) { in = in0; out = out0; }
    else          { in = in1; out = out1; z -= cnt0; }
    const long base = (long)z * Rr * Cc;
    const int r0 = blockIdx.y * 64, c0 = blockIdx.x * 64;
    #pragma unroll
    for (int i = 0; i < 16; ++i) {
        int e = tid + i * 256; int row = e >> 6, col = e & 63;
        Ls[row][col] = in[base + (long)(r0 + row) * Cc + c0 + col];
    }
    __syncthreads();
    #pragma unroll
    for (int i = 0; i < 16; ++i) {
        int e = tid + i * 256; int row = e >> 6, col = e & 63;
        out[base + (long)(c0 + row) * Rr + r0 + col] = f2bf(Ls[col][row]);
    }
}

__global__ __launch_bounds__(256) void transconv_kernel(
    const float* __restrict__ in, bf16_t* __restrict__ out, int Rr, int Cc)
{
    __shared__ float Ls[64][65];
    const int tid = threadIdx.x;
    const long base = (long)blockIdx.z * Rr * Cc;
    const int r0 = blockIdx.y * 64, c0 = blockIdx.x * 64;
    #pragma unroll
    for (int i = 0; i < 16; ++i) {
        int e = tid + i * 256; int row = e >> 6, col = e & 63;
        Ls[row][col] = in[base + (long)(r0 + row) * Cc + c0 + col];
    }
    __syncthreads();
    #pragma unroll
    for (int i = 0; i < 16; ++i) {
        int e = tid + i * 256; int row = e >> 6, col = e & 63;
        out[base + (long)(c0 + row) * Rr + r0 + col] = f2bf(Ls[col][row]);
    }
}

// ---------------- fused relation weights (+bias, folded) ----------------
__global__ __launch_bounds__(256) void fuse_wT_kernel(
    const float* __restrict__ Wk, const float* __restrict__ Wv,
    const float* __restrict__ bk, const float* __restrict__ bv,
    const float* __restrict__ a_rel, const float* __restrict__ m_rel,
    bf16_t* __restrict__ WkvT, float* __restrict__ bkv)
{
    const int s = blockIdx.z;
    const int kv = s & 1, r = (s >> 1) & 3, l = s >> 3;
    const int SRCT[4] = {0, 1, 1, 1};
    const int st = SRCT[r];
    const float* W = (kv ? Wv : Wk) + ((long)l * T_ + st) * H_ * H_;
    const float* A = (kv ? m_rel : a_rel) + ((long)l * R_ + r) * HEADS_ * D_ * D_;
    const int hh = blockIdx.y, kt = blockIdx.x;
    __shared__ float As[32][33];
    __shared__ float Ws[64][33];
    const int tid = threadIdx.x;
    {
        int d = tid >> 3, e4 = (tid & 7) * 4;
        float4 v = *(const float4*)(A + (hh * D_ + d) * D_ + e4);
        As[d][e4] = v.x; As[d][e4 + 1] = v.y; As[d][e4 + 2] = v.z; As[d][e4 + 3] = v.w;
    }
    #pragma unroll
    for (int p = 0; p < 2; ++p) {
        int idx = p * 256 + tid;
        int row = idx >> 3, c4 = (idx & 7) * 4;
        float4 v = *(const float4*)(W + (long)(kt * 64 + row) * H_ + hh * 32 + c4);
        Ws[row][c4] = v.x; Ws[row][c4 + 1] = v.y; Ws[row][c4 + 2] = v.z; Ws[row][c4 + 3] = v.w;
    }
    __syncthreads();
    const int kl = tid & 63, eb = tid >> 6;
    #pragma unroll
    for (int ii = 0; ii < 8; ++ii) {
        int e = eb * 8 + ii;
        float acc = 0.f;
        #pragma unroll
        for (int d = 0; d < 32; ++d)
            acc += As[d][e] * Ws[kl][d];
        long rowIdx = (long)(s >> 1) * 512 + (kv * 256) + hh * 32 + e;
        WkvT[rowIdx * H_ + kt * 64 + kl] = f2bf(acc);
    }
    if (blockIdx.x == 0 && blockIdx.y == 0) {
        const float* b = (kv ? bv : bk) + ((long)l * T_ + st) * H_;
        const int bh = tid >> 5, be = tid & 31;
        float acc = 0.f;
        #pragma unroll
        for (int d = 0; d < D_; ++d)
            acc += b[bh * D_ + d] * A[(bh * D_ + d) * D_ + be];
        bkv[(long)(s >> 1) * 512 + kv * 256 + tid] = acc;
    }
}

// ---------------- CSR build (parallel scan) ----------------
__global__ void hist_kernel(const int* __restrict__ ei, int* __restrict__ indeg,
                            int Nn, int E)
{
    int idx = blockIdx.x * 256 + threadIdx.x;
    if (idx >= R_ * E) return;
    int r = idx / E, e = idx - r * E;
    int d = ei[(size_t)r * 2 * E + E + e];
    atomicAdd(indeg + (size_t)r * Nn + d, 1);
}

__global__ __launch_bounds__(256) void csr_part_kernel(
    const int* __restrict__ indeg, int* __restrict__ partials, int Nn, int nch)
{
    const int r = blockIdx.y, c = blockIdx.x, tid = threadIdx.x;
    const int lane = tid & 63, wave = tid >> 6;
    int idx = c * 256 + tid;
    int v = (idx < Nn) ? indeg[(size_t)r * Nn + idx] : 0;
    #pragma unroll
    for (int off = 1; off < 64; off <<= 1) v += __shfl_xor(v, off);
    __shared__ int wsum[4];
    if (lane == 0) wsum[wave] = v;
    __syncthreads();
    if (tid == 0) partials[r * nch + c] = wsum[0] + wsum[1] + wsum[2] + wsum[3];
}

__global__ __launch_bounds__(256) void csr_scanpart_kernel(
    int* __restrict__ partials, int nch)
{
    const int r = blockIdx.x, tid = threadIdx.x;
    __shared__ int sh[256];
    int v = (tid < nch) ? partials[r * nch + tid] : 0;
    sh[tid] = v;
    __syncthreads();
    for (int off = 1; off < 256; off <<= 1) {
        int u = (tid >= off) ? sh[tid - off] : 0;
        __syncthreads();
        sh[tid] += u;
        __syncthreads();
    }
    if (tid < nch) partials[r * nch + tid] = sh[tid] - v;   // exclusive
}

__global__ __launch_bounds__(256) void csr_write_kernel(
    const int* __restrict__ indeg, const int* __restrict__ partials,
    int* __restrict__ offs, int* __restrict__ cursor, int Nn, int nch)
{
    const int r = blockIdx.y, c = blockIdx.x, tid = threadIdx.x;
    int idx = c * 256 + tid;
    int v = (idx < Nn) ? indeg[(size_t)r * Nn + idx] : 0;
    __shared__ int sh[256];
    sh[tid] = v;
    __syncthreads();
    for (int off = 1; off < 256; off <<= 1) {
        int u = (tid >= off) ? sh[tid - off] : 0;
        __syncthreads();
        sh[tid] += u;
        __syncthreads();
    }
    int incl = sh[tid];
    int base = partials[r * nch + c];
    if (idx < Nn) {
        int excl = base + incl - v;
        offs[(size_t)r * (Nn + 1) + idx] = excl;
        cursor[(size_t)r * Nn + idx] = excl;
        if (idx == Nn - 1) offs[(size_t)r * (Nn + 1) + Nn] = base + incl;
    }
}

// esrc stores PRE-SCALED element offsets (src * 512) into a KV relation slice
__global__ void scatter_kernel(const int* __restrict__ ei, int* __restrict__ cursor,
                               int* __restrict__ esrc, int Nn, int E)
{
    int idx = blockIdx.x * 256 + threadIdx.x;
    if (idx >= R_ * E) return;
    int r = idx / E, e = idx - r * E;
    int s = ei[(size_t)r * 2 * E + e];
    int d = ei[(size_t)r * 2 * E + E + e];
    int pos = atomicAdd(cursor + (size_t)r * Nn + d, 1);
    esrc[(size_t)r * E + pos] = s * 512;
}

// ---------------- batched per-node attention aggregation ----------------
// Dual-chain (scalar state, NO runtime-indexed arrays — rule #20), with
// depth-2 software prefetch per chain (next edge's K/V rows issued before
// current edge's compute) and deferred-max common path.
// Per-relation INDEPENDENT softmax; normalized results summed (matches ref).
#define CHAIN_STEP(ku, vu, prX, mX, sX, x0, x1, x2, x3)                     \
    {                                                                        \
        float dt_ = q0 * bflo(ku.x) + q1 * bfhi(ku.x)                        \
                  + q2 * bflo(ku.y) + q3 * bfhi(ku.y);                       \
        dt_ += __shfl_xor(dt_, 1);                                           \
        dt_ += __shfl_xor(dt_, 2);                                           \
        dt_ += __shfl_xor(dt_, 4);                                           \
        float lg = dt_ * prX;                                                \
        if (__any(lg - mX > 8.f)) {                                          \
            float mn = fmaxf(mX, lg);                                        \
            float fac = __expf(mX - mn);                                     \
            float p = __expf(lg - mn);                                       \
            sX = sX * fac + p;                                               \
            x0 = x0 * fac + p * bflo(vu.x);                                  \
            x1 = x1 * fac + p * bfhi(vu.x);                                  \
            x2 = x2 * fac + p * bflo(vu.y);                                  \
            x3 = x3 * fac + p * bfhi(vu.y);                                  \
            mX = mn;                                                         \
        } else {                                                             \
            float p = __expf(lg - mX);                                       \
            sX += p;                                                         \
            x0 += p * bflo(vu.x);                                            \
            x1 += p * bfhi(vu.x);                                            \
            x2 += p * bflo(vu.y);                                            \
            x3 += p * bfhi(vu.y);                                            \
        }                                                                    \
    }

__global__ __launch_bounds__(512) void agg_all_kernel(
    const int* __restrict__ offs, const int* __restrict__ esrc,
    bf16_t* __restrict__ qbuf, const bf16_t* __restrict__ KV,
    const float* __restrict__ p_l, float scale, int Nn, int E)
{
    static const int NRELg[3] = {2, 1, 1};
    static const int R0g[3]  = {0, 1, 3};
    static const int R1g[3]  = {2, 0, 0};
    static const int DTg[3]  = {1, 0, 2};
    const int grp = blockIdx.y;
    const int wave = threadIdx.x >> 6, lane = threadIdx.x & 63;
    const int d = blockIdx.x * 8 + wave;
    if (d >= Nn) return;
    const int head = lane >> 3;
    const int dt = DTg[grp];
    const bool separate = (NRELg[grp] == 2);

    bf16_t* qrow = qbuf + ((size_t)dt * Nn + d) * H_;
    uint2 qu = ((const uint2*)qrow)[lane];
    float q0 = bflo(qu.x), q1 = bfhi(qu.x), q2 = bflo(qu.y), q3 = bfhi(qu.y);

    const int rA = R0g[grp];
    const int* esA = esrc + (size_t)rA * E;
    const bf16_t* kvA = KV + (size_t)rA * Nn * 512;
    float prA = p_l[rA * HEADS_ + head] * scale;
    int curA = offs[(size_t)rA * (Nn + 1) + d];
    int endA = offs[(size_t)rA * (Nn + 1) + d + 1];

    const int* esB; const bf16_t* kvB; float prB;
    int curB, endB;
    if (separate) {
        const int rB = R1g[grp];
        esB = esrc + (size_t)rB * E;
        kvB = KV + (size_t)rB * Nn * 512;
        prB = p_l[rB * HEADS_ + head] * scale;
        curB = offs[(size_t)rB * (Nn + 1) + d];
        endB = offs[(size_t)rB * (Nn + 1) + d + 1];
    } else {
        int mid = curA + ((endA - curA + 1) >> 1);
        esB = esA; kvB = kvA; prB = prA;
        curB = mid; endB = endA;
        endA = mid;
    }

    float mA = -INFINITY, sA = 0.f, aA0 = 0.f, aA1 = 0.f, aA2 = 0.f, aA3 = 0.f;
    float mB = -INFINITY, sB = 0.f, aB0 = 0.f, aB1 = 0.f, aB2 = 0.f, aB3 = 0.f;

    bool hA = curA < endA, hB = curB < endB;
    uint2 kA, vA, kB, vB;
    if (hA) {
        const bf16_t* r = kvA + esA[curA];
        kA = ((const uint2*)r)[lane]; vA = ((const uint2*)(r + 256))[lane];
    }
    if (hB) {
        const bf16_t* r = kvB + esB[curB];
        kB = ((const uint2*)r)[lane]; vB = ((const uint2*)(r + 256))[lane];
    }

    while (hA || hB) {
        // prefetch next edges (loads issue before current compute)
        bool nA = hA && (curA + 1 < endA);
        bool nB = hB && (curB + 1 < endB);
        uint2 kA2, vA2, kB2, vB2;
        if (nA) {
            const bf16_t* r = kvA + esA[curA + 1];
            kA2 = ((const uint2*)r)[lane]; vA2 = ((const uint2*)(r + 256))[lane];
        }
        if (nB) {
            const bf16_t* r = kvB + esB[curB + 1];
            kB2 = ((const uint2*)r)[lane]; vB2 = ((const uint2*)(r + 256))[lane];
        }
        if (hA) { CHAIN_STEP(kA, vA, prA, mA, sA, aA0, aA1, aA2, aA3) ++curA; }
        if (hB) { CHAIN_STEP(kB, vB, prB, mB, sB, aB0, aB1, aB2, aB3) ++curB; }
        kA = kA2; vA = vA2; kB = kB2; vB = vB2;
        hA = nA; hB = nB;
    }

    float t0, t1, t2, t3;
    if (separate) {
        float iA = (sA > 0.f) ? 1.f / sA : 0.f;
        float iB = (sB > 0.f) ? 1.f / sB : 0.f;
        t0 = aA0 * iA + aB0 * iB;
        t1 = aA1 * iA + aB1 * iB;
        t2 = aA2 * iA + aB2 * iB;
        t3 = aA3 * iA + aB3 * iB;
    } else {
        if (sB > 0.f) {   // exact merge of the two half-range chains
            float mm = fmaxf(mA, mB);
            float fx = (sA > 0.f) ? __expf(mA - mm) : 0.f;
            float fy = __expf(mB - mm);
            sA = sA * fx + sB * fy;
            aA0 = aA0 * fx + aB0 * fy;
            aA1 = aA1 * fx + aB1 * fy;
            aA2 = aA2 * fx + aB2 * fy;
            aA3 = aA3 * fx + aB3 * fy;
        }
        float iA = (sA > 0.f) ? 1.f / sA : 0.f;
        t0 = aA0 * iA; t1 = aA1 * iA; t2 = aA2 * iA; t3 = aA3 * iA;
    }
    ushort4 ou;
    ou.x = f2bf(gelu_exact(t0));
    ou.y = f2bf(gelu_exact(t1));
    ou.z = f2bf(gelu_exact(t2));
    ou.w = f2bf(gelu_exact(t3));
    ((ushort4*)qrow)[lane] = ou;
}

// ---------------- MFMA bf16 GEMM ----------------
#define ASTR 40
#define ESTR 72

template<typename TA, typename TC, int ACT_C>
__global__ __launch_bounds__(256) void mfma_gemm(
    const TA* __restrict__ A, const TA* __restrict__ A2, int zsplit,
    const bf16_t* __restrict__ BT,
    const float* __restrict__ bias, TC* __restrict__ C,
    int M, int K, int Nc,
    long strideA, long strideB, long strideBias, long strideC)
{
    const int gX = gridDim.x, gY = gridDim.y, gZ = gridDim.z;
    const int nwg = gX * gY * gZ;
    int flat = blockIdx.x + gX * (blockIdx.y + gY * blockIdx.z);
    const int qch = nwg >> 3, rch = nwg & 7;
    int xcd = flat & 7, cidx = flat >> 3;
    int swz = (xcd < rch ? xcd * (qch + 1) : rch * (qch + 1) + (xcd - rch) * qch) + cidx;
    const int by = swz / (gX * gZ);
    int rem = swz - by * (gX * gZ);
    const int bz = rem / gX;
    const int bx = rem - bz * gX;

    const TA* Ab = (bz < zsplit) ? (A + (long)bz * strideA) : A2;
    const bf16_t* Bb = BT + (long)bz * strideB;
    const float* biasb = bias + (long)bz * strideBias;
    TC* Cb = C + (long)bz * strideC;

    __shared__ bf16_t As[128 * ASTR];
    __shared__ bf16_t Bs[128 * ASTR];
    __shared__ bf16_t Es[4 * 16 * ESTR];
    const int tid = threadIdx.x;
    const int lane = tid & 63, wave = tid >> 6;
    const int wr = wave >> 1, wc = wave & 1;
    const int bm = by * 128, bn = bx * 128;
    const int r16 = lane & 15, g = lane >> 4;
    f32x4 acc[4][4] = {};

    for (int k0 = 0; k0 < K; k0 += 32) {
        #pragma unroll
        for (int p = 0; p < 2; ++p) {
            int idx = p * 256 + tid;
            int row = idx >> 2, seg = idx & 3;
            int grow = bm + row;
            bf16x8 av = {};
            if (grow < M) {
                if constexpr (sizeof(TA) == 2) {
                    av = *(const bf16x8*)(Ab + (long)grow * K + k0 + seg * 8);
                } else {
                    const float* sp = (const float*)Ab + (long)grow * K + k0 + seg * 8;
                    float4 f0 = *(const float4*)sp, f1 = *(const float4*)(sp + 4);
                    av[0] = (short)f2bf(f0.x); av[1] = (short)f2bf(f0.y);
                    av[2] = (short)f2bf(f0.z); av[3] = (short)f2bf(f0.w);
                    av[4] = (short)f2bf(f1.x); av[5] = (short)f2bf(f1.y);
                    av[6] = (short)f2bf(f1.z); av[7] = (short)f2bf(f1.w);
                }
            }
            *(bf16x8*)(As + row * ASTR + seg * 8) = av;
            bf16x8 bv = *(const bf16x8*)(Bb + (long)(bn + row) * K + k0 + seg * 8);
            *(bf16x8*)(Bs + row * ASTR + seg * 8) = bv;
        }
        __syncthreads();
        bf16x8 af[4], bfr[4];
        #pragma unroll
        for (int m = 0; m < 4; ++m)
            af[m] = *(const bf16x8*)(As + (wr * 64 + m * 16 + r16) * ASTR + g * 8);
        #pragma unroll
        for (int n = 0; n < 4; ++n)
            bfr[n] = *(const bf16x8*)(Bs + (wc * 64 + n * 16 + r16) * ASTR + g * 8);
        #pragma unroll
        for (int m = 0; m < 4; ++m)
            #pragma unroll
            for (int n = 0; n < 4; ++n)
                acc[m][n] = __builtin_amdgcn_mfma_f32_16x16x32_bf16(af[m], bfr[n], acc[m][n], 0, 0, 0);
        __syncthreads();
    }

    float bb[4];
    #pragma unroll
    for (int n = 0; n < 4; ++n)
        bb[n] = biasb[bn + wc * 64 + n * 16 + r16];

    if constexpr (sizeof(TC) == 2) {
        bf16_t* st = Es + wave * (16 * ESTR);
        #pragma unroll
        for (int m = 0; m < 4; ++m) {
            int rowbase = bm + wr * 64 + m * 16;
            #pragma unroll
            for (int n = 0; n < 4; ++n) {
                #pragma unroll
                for (int j = 0; j < 4; ++j) {
                    float vv = acc[m][n][j] + bb[n];
                    if (ACT_C) vv = fmaxf(vv, 0.f);
                    st[(g * 4 + j) * ESTR + n * 16 + r16] = f2bf(vv);
                }
            }
            #pragma unroll
            for (int p = 0; p < 2; ++p) {
                int row = p * 8 + (lane >> 3);
                int col0 = (lane & 7) * 8;
                int grow = rowbase + row;
                bf16x8 val = *(const bf16x8*)(st + row * ESTR + col0);
                if (grow < M)
                    *(bf16x8*)(Cb + (long)grow * Nc + bn + wc * 64 + col0) = val;
            }
        }
    } else {
        #pragma unroll
        for (int n = 0; n < 4; ++n) {
            int col = bn + wc * 64 + n * 16 + r16;
            #pragma unroll
            for (int m = 0; m < 4; ++m) {
                int rowbase = bm + wr * 64 + m * 16 + g * 4;
                #pragma unroll
                for (int j = 0; j < 4; ++j) {
                    int row = rowbase + j;
                    if (row < M) {
                        float vv = acc[m][n][j] + bb[n];
                        if (ACT_C) vv = fmaxf(vv, 0.f);
                        Cb[(long)row * Nc + col] = vv;
                    }
                }
            }
        }
    }
}

// ---------------- fused skip-gate + residual + LN + ReLU ----------------
__global__ __launch_bounds__(256) void skip_ln_kernel(
    bf16_t* __restrict__ h, const bf16_t* __restrict__ o,
    const float* __restrict__ skip, const float* __restrict__ ln_g,
    const float* __restrict__ ln_b, int Nn)
{
    const int wave = threadIdx.x >> 6;
    const int lane = threadIdx.x & 63;
    long row = (long)blockIdx.x * 4 + wave;
    long total = (long)T_ * Nn;
    if (row >= total) return;
    int t = (int)(row / Nn);
    float beta = 1.f / (1.f + expf(-skip[t]));
    float cb = 2.f - beta;
    ushort4 hv = reinterpret_cast<const ushort4*>(h + row * H_)[lane];
    ushort4 ov = reinterpret_cast<const ushort4*>(o + row * H_)[lane];
    float u0 = beta * bf2f(ov.x) + cb * bf2f(hv.x);
    float u1 = beta * bf2f(ov.y) + cb * bf2f(hv.y);
    float u2 = beta * bf2f(ov.z) + cb * bf2f(hv.z);
    float u3 = beta * bf2f(ov.w) + cb * bf2f(hv.w);
    float s1 = u0 + u1 + u2 + u3;
    float s2 = u0 * u0 + u1 * u1 + u2 * u2 + u3 * u3;
    #pragma unroll
    for (int off = 1; off < 64; off <<= 1) {
        s1 += __shfl_xor(s1, off);
        s2 += __shfl_xor(s2, off);
    }
    float mu = s1 * (1.f / H_);
    float var = s2 * (1.f / H_) - mu * mu;
    float inv = rsqrtf(var + 1e-5f);
    const float4 g = reinterpret_cast<const float4*>(ln_g + (size_t)t * H_)[lane];
    const float4 b = reinterpret_cast<const float4*>(ln_b + (size_t)t * H_)[lane];
    ushort4 r;
    r.x = f2bf(fmaxf((u0 - mu) * inv * g.x + b.x, 0.f));
    r.y = f2bf(fmaxf((u1 - mu) * inv * g.y + b.y, 0.f));
    r.z = f2bf(fmaxf((u2 - mu) * inv * g.z + b.z, 0.f));
    r.w = f2bf(fmaxf((u3 - mu) * inv * g.w + b.w, 0.f));
    reinterpret_cast<ushort4*>(h + row * H_)[lane] = r;
}

// ---------------- host side ----------------
extern "C" void kernel_launch(void* const* d_in, const int* in_sizes, int n_in,
                              void* d_out, int out_size, void* d_ws, size_t ws_size,
                              hipStream_t stream)
{
    const float* x     = (const float*)d_in[0];
    const int*   ei    = (const int*)  d_in[1];
    const float* Win   = (const float*)d_in[2];
    const float* b_in  = (const float*)d_in[3];
    const float* Wk    = (const float*)d_in[4];
    const float* bk    = (const float*)d_in[5];
    const float* Wq    = (const float*)d_in[6];
    const float* bq    = (const float*)d_in[7];
    const float* Wv    = (const float*)d_in[8];
    const float* bv    = (const float*)d_in[9];
    const float* Wa    = (const float*)d_in[10];
    const float* ba    = (const float*)d_in[11];
    const float* skip  = (const float*)d_in[12];
    const float* a_rel = (const float*)d_in[13];
    const float* m_rel = (const float*)d_in[14];
    const float* p_rel = (const float*)d_in[15];
    const float* ln_g  = (const float*)d_in[16];
    const float* ln_b  = (const float*)d_in[17];
    const float* Wout  = (const float*)d_in[18];
    const float* bout  = (const float*)d_in[19];
    float* out = (float*)d_out;

    const int N = in_sizes[0] / (T_ * FIN_);
    const int E = in_sizes[1] / (R_ * 2);
    const size_t NH = (size_t)N * H_;
    const int nch = (N + 255) / 256;
    const int ZBIG = 1 << 20;

    char* wp = (char*)d_ws;
    auto alloc = [&](size_t bytes) {
        void* r = wp;
        wp += (bytes + 255) & ~(size_t)255;
        return r;
    };
    bf16_t* h     = (bf16_t*)alloc(T_ * NH * 2);
    bf16_t* qbuf  = (bf16_t*)alloc(T_ * NH * 2);
    bf16_t* KV    = (bf16_t*)alloc((size_t)R_ * N * 512 * 2);
    int*    indeg = (int*)   alloc((size_t)R_ * N * 4);
    int*    offs  = (int*)   alloc((size_t)R_ * (N + 1) * 4);
    int*    cursor= (int*)   alloc((size_t)R_ * N * 4);
    int*    esrc  = (int*)   alloc((size_t)R_ * E * 4);
    int*    parts = (int*)   alloc((size_t)R_ * 256 * 4);
    bf16_t* WqT   = (bf16_t*)alloc((size_t)L_ * T_ * H_ * H_ * 2);
    bf16_t* WaT   = (bf16_t*)alloc((size_t)L_ * T_ * H_ * H_ * 2);
    bf16_t* WinT  = (bf16_t*)alloc((size_t)T_ * FIN_ * H_ * 2);
    bf16_t* WoutT = (bf16_t*)alloc((size_t)H_ * OUT_ * 2);
    bf16_t* WkvT  = (bf16_t*)alloc((size_t)L_ * R_ * 512 * H_ * 2);
    float*  bkv   = (float*) alloc((size_t)L_ * R_ * 512 * 4);

    bf16_t* obuf = KV;   // reuse of KV after agg consumes it

    if ((size_t)(wp - (char*)d_ws) > ws_size) return;   // clean-fail guard

    const float scale = 0.17677669529663688f;  // 1/sqrt(32)
    dim3 blk(256);
    auto gM = [](long M) { return (int)((M + 127) / 128); };

    // ---- weight preprocessing ----
    transconv2_kernel<<<dim3(4, 4, 2 * L_ * T_), blk, 0, stream>>>(
        Wq, WqT, Wa, WaT, L_ * T_, H_, H_);
    transconv_kernel<<<dim3(4, 2, T_), blk, 0, stream>>>(Win, WinT, FIN_, H_);
    transconv_kernel<<<dim3(2, 4, 1),  blk, 0, stream>>>(Wout, WoutT, H_, OUT_);
    fuse_wT_kernel<<<dim3(4, 8, 16), blk, 0, stream>>>(
        Wk, Wv, bk, bv, a_rel, m_rel, WkvT, bkv);

    // ---- CSR build (parallel) ----
    zero_kernel<<<256, blk, 0, stream>>>((unsigned*)indeg, (long)R_ * N);
    hist_kernel<<<(R_ * E + 255) / 256, blk, 0, stream>>>(ei, indeg, N, E);
    csr_part_kernel<<<dim3(nch, R_), blk, 0, stream>>>(indeg, parts, N, nch);
    csr_scanpart_kernel<<<R_, blk, 0, stream>>>(parts, nch);
    csr_write_kernel<<<dim3(nch, R_), blk, 0, stream>>>(indeg, parts, offs, cursor, N, nch);
    scatter_kernel<<<(R_ * E + 255) / 256, blk, 0, stream>>>(ei, cursor, esrc, N, E);

    // ---- input projection + relu ----
    mfma_gemm<float, bf16_t, 1><<<dim3(H_ / 128, gM(N), T_), blk, 0, stream>>>(
        x, x, ZBIG, WinT, b_in, h, N, FIN_, H_,
        (long)N * FIN_, (long)FIN_ * H_, H_, (long)NH);

    for (int l = 0; l < L_; ++l) {
        const long lw = (long)l * R_;
        // KV for all 4 relations in one z=4 launch
        mfma_gemm<bf16_t, bf16_t, 0><<<dim3(512 / 128, gM(N), 4), blk, 0, stream>>>(
            h, h + NH, 1, WkvT + lw * 512 * H_, bkv + lw * 512, KV,
            N, H_, 512, 0L, 512L * H_, 512L, (long)N * 512);
        // q for all 3 node types: z=3
        mfma_gemm<bf16_t, bf16_t, 0><<<dim3(H_ / 128, gM(N), 3), blk, 0, stream>>>(
            h, h, ZBIG, WqT + (size_t)l * T_ * H_ * H_, bq + (size_t)l * T_ * H_, qbuf,
            N, H_, H_, (long)NH, (long)H_ * H_, (long)H_, (long)NH);
        // batched per-node per-relation softmax aggregation + GELU (in place)
        agg_all_kernel<<<dim3((N + 7) / 8, 3), dim3(512), 0, stream>>>(
            offs, esrc, qbuf, KV, p_rel + (size_t)l * R_ * HEADS_, scale, N, E);
        // o[t] = aggb[t] @ Wa[t] + ba[t] : z=3
        mfma_gemm<bf16_t, bf16_t, 0><<<dim3(H_ / 128, gM(N), 3), blk, 0, stream>>>(
            qbuf, qbuf, ZBIG, WaT + (size_t)l * T_ * H_ * H_, ba + (size_t)l * T_ * H_, obuf,
            N, H_, H_, (long)NH, (long)H_ * H_, (long)H_, (long)NH);
        // skip-gate + residual + LN + ReLU
        skip_ln_kernel<<<((size_t)T_ * N + 3) / 4, blk, 0, stream>>>(
            h, obuf, skip + l * T_, ln_g + (size_t)l * T_ * H_, ln_b + (size_t)l * T_ * H_, N);
    }

    // shared output projection: h bf16 -> out fp32
    mfma_gemm<bf16_t, float, 0><<<dim3(OUT_ / 128, gM((long)T_ * N), 1), blk, 0, stream>>>(
        h, h, ZBIG, WoutT, bout, out, T_ * N, H_, OUT_, 0L, 0L, 0L, 0L);
}